// Round 1
// baseline (1127.062 us; speedup 1.0000x reference)
//
#include <hip/hip_runtime.h>

typedef unsigned int u32;
typedef unsigned short u16;
typedef __attribute__((ext_vector_type(8))) short short8;   // 8 bf16 (4 VGPRs)
typedef __attribute__((ext_vector_type(4))) float f32x4;

#define DEV __device__ __forceinline__

DEV u16 f2bf(float f) {
    u32 u = __float_as_uint(f);
    return (u16)((u + 0x7FFFu + ((u >> 16) & 1u)) >> 16);
}
DEV float bf2f(u16 h) { return __uint_as_float(((u32)h) << 16); }
DEV float frcp(float x) { return __builtin_amdgcn_rcpf(x); }
// extract r-th bf16 (r constant under unroll) from packed uint2
DEV float xex(uint2 v, int r) {
    u32 u = (r & 2) ? v.y : v.x;
    return (r & 1) ? __uint_as_float(u & 0xFFFF0000u) : __uint_as_float(u << 16);
}

// ---------------------------------------------------------------------------
// K1: embedding gather + input projection.  X[s,g4,m,rg,col,r4] bf16, swizzled
// to match MFMA C-fragment layout used by k_lstm.  One launch per direction.
// block=256 handles 16 positions (one s, one 16-batch group) x 512 gates.
// ---------------------------------------------------------------------------
__global__ __launch_bounds__(256) void k_inproj(
    const int* __restrict__ sent, const float* __restrict__ emb,
    const float* __restrict__ wih, const float* __restrict__ bih,
    const float* __restrict__ bhh, u16* __restrict__ X)
{
    __shared__ float al[16][132];   // 16 emb rows, padded (+4) for bank spread
    __shared__ int  toks[16];
    int tid = threadIdx.x;
    int pos_base = blockIdx.x * 16;           // pos = s*64 + b
    int s  = pos_base >> 6;
    int g4 = (pos_base & 63) >> 4;
    if (tid < 16) toks[tid] = sent[pos_base + tid];
    __syncthreads();
    {
        int p = tid >> 4, kk = (tid & 15) * 8;
        const float* er = emb + (size_t)toks[p] * 128 + kk;
        float4 e0 = *(const float4*)er;
        float4 e1 = *(const float4*)(er + 4);
        *(float4*)&al[p][kk]     = e0;
        *(float4*)&al[p][kk + 4] = e1;
    }
    __syncthreads();
    int col = tid & 15, qg = tid >> 4;
    for (int outer = 0; outer < 8; ++outer) {
        int gq = outer * 16 + qg;       // gate quad index, gates 4gq..4gq+3
        int g0 = gq * 4;
        float a0 = 0.f, a1 = 0.f, a2 = 0.f, a3 = 0.f;
        const float* w0p = wih + (size_t)g0 * 128;
        #pragma unroll 4
        for (int k = 0; k < 128; k += 4) {
            float4 a  = *(const float4*)&al[col][k];
            float4 w0 = *(const float4*)(w0p + k);
            float4 w1 = *(const float4*)(w0p + 128 + k);
            float4 w2 = *(const float4*)(w0p + 256 + k);
            float4 w3 = *(const float4*)(w0p + 384 + k);
            a0 += a.x*w0.x + a.y*w0.y + a.z*w0.z + a.w*w0.w;
            a1 += a.x*w1.x + a.y*w1.y + a.z*w1.z + a.w*w1.w;
            a2 += a.x*w2.x + a.y*w2.y + a.z*w2.z + a.w*w2.w;
            a3 += a.x*w3.x + a.y*w3.y + a.z*w3.z + a.w*w3.w;
        }
        a0 += bih[g0]     + bhh[g0];
        a1 += bih[g0 + 1] + bhh[g0 + 1];
        a2 += bih[g0 + 2] + bhh[g0 + 2];
        a3 += bih[g0 + 3] + bhh[g0 + 3];
        // m = gq>>2, rg = gq&3, r4 = 0..3
        size_t idx = ((((size_t)s * 4 + g4) * 32 + (gq >> 2)) * 4 + (gq & 3)) * 64
                     + (size_t)col * 4;
        uint2 st;
        st.x = (u32)f2bf(a0) | ((u32)f2bf(a1) << 16);
        st.y = (u32)f2bf(a2) | ((u32)f2bf(a3) << 16);
        *(uint2*)(X + idx) = st;
    }
}

// ---------------------------------------------------------------------------
// K2: bidirectional LSTM recurrence.  8 blocks = 2 dirs x 4 batch-groups(16).
// W_hh lives in per-wave A-fragments (VGPRs) for the whole kernel; h round-
// trips a 4KB double-buffered LDS tile per step.  c stays in registers.
// Writes h (bf16) to global for the feats kernel.
// ---------------------------------------------------------------------------
__global__ __launch_bounds__(512) void k_lstm(
    const float* __restrict__ h0, const float* __restrict__ c0,
    const float* __restrict__ whhf, const float* __restrict__ whhb,
    const u16* __restrict__ Xf, const u16* __restrict__ Xb,
    u16* __restrict__ hfo, u16* __restrict__ hbo)
{
    int d  = blockIdx.x >> 2, g4 = blockIdx.x & 3;
    const float* whh = d ? whhb : whhf;
    const u16*   X   = d ? Xb   : Xf;
    u16*         ho  = d ? hbo  : hfo;
    int w = threadIdx.x >> 6, lane = threadIdx.x & 63;
    int rg = lane >> 4, cn = lane & 15;

    // A-fragments: wave w owns M-tiles {w, w+8, w+16, w+24} = i/f/g/o gates of
    // channels 16w..16w+15.  A[m][k]: row m = lane&15, k = (lane>>4)*8 + j.
    short8 afr[4][4];
    #pragma unroll
    for (int mi = 0; mi < 4; ++mi) {
        int gate = 16 * (w + 8 * mi) + cn;
        #pragma unroll
        for (int kt = 0; kt < 4; ++kt) {
            const float* p = whh + (size_t)gate * 128 + kt * 32 + rg * 8;
            float4 f0 = *(const float4*)p;
            float4 f1 = *(const float4*)(p + 4);
            union { short8 v; u16 u[8]; } sv;
            sv.u[0]=f2bf(f0.x); sv.u[1]=f2bf(f0.y); sv.u[2]=f2bf(f0.z); sv.u[3]=f2bf(f0.w);
            sv.u[4]=f2bf(f1.x); sv.u[5]=f2bf(f1.y); sv.u[6]=f2bf(f1.z); sv.u[7]=f2bf(f1.w);
            afr[mi][kt] = sv.v;
        }
    }
    int b = g4 * 16 + cn;           // batch index this lane's column holds
    int chb = 16 * w + rg * 4;      // first of 4 channels this lane holds
    float cst[4];
    {
        float4 cv = *(const float4*)(c0 + ((size_t)d * 64 + b) * 128 + chb);
        cst[0]=cv.x; cst[1]=cv.y; cst[2]=cv.z; cst[3]=cv.w;
    }
    __shared__ u16 hbuf[2][16][136];   // [buf][n=batch][k=channel], +8 pad
    {
        float4 hv = *(const float4*)(h0 + ((size_t)d * 64 + b) * 128 + chb);
        uint2 st;
        st.x = (u32)f2bf(hv.x) | ((u32)f2bf(hv.y) << 16);
        st.y = (u32)f2bf(hv.z) | ((u32)f2bf(hv.w) << 16);
        *(uint2*)&hbuf[0][cn][chb] = st;
    }
    __syncthreads();

    size_t lof = (size_t)rg * 64 + (size_t)cn * 4;
    uint2 xc[4];
    {
        int s0 = d ? 511 : 0;
        #pragma unroll
        for (int mi = 0; mi < 4; ++mi)
            xc[mi] = *(const uint2*)(X + (((size_t)s0*4 + g4)*32 + (w + 8*mi))*256 + lof);
    }

    for (int t = 0; t < 512; ++t) {
        int s  = d ? (511 - t) : t;
        int sn = d ? (s > 0 ? s - 1 : 0) : (s < 511 ? s + 1 : 511);
        uint2 xn[4];                               // prefetch next step's X
        #pragma unroll
        for (int mi = 0; mi < 4; ++mi)
            xn[mi] = *(const uint2*)(X + (((size_t)sn*4 + g4)*32 + (w + 8*mi))*256 + lof);

        int cur = t & 1;
        short8 bfr[4];                             // B[k][n]: n=lane&15, k=(lane>>4)*8+j
        #pragma unroll
        for (int kt = 0; kt < 4; ++kt)
            bfr[kt] = *(const short8*)&hbuf[cur][cn][kt * 32 + rg * 8];

        f32x4 z[4];
        #pragma unroll
        for (int mi = 0; mi < 4; ++mi) {
            f32x4 acc = {0.f, 0.f, 0.f, 0.f};
            #pragma unroll
            for (int kt = 0; kt < 4; ++kt)
                acc = __builtin_amdgcn_mfma_f32_16x16x32_bf16(afr[mi][kt], bfr[kt], acc, 0, 0, 0);
            z[mi] = acc;
        }

        float hnew[4];
        #pragma unroll
        for (int r = 0; r < 4; ++r) {
            float zi = z[0][r] + xex(xc[0], r);
            float zf = z[1][r] + xex(xc[1], r);
            float zg = z[2][r] + xex(xc[2], r);
            float zo = z[3][r] + xex(xc[3], r);
            float ei = __expf(-zi);
            float ef = __expf(-zf);
            float eo = __expf(-zo);
            float eg = __expf(fminf(2.f * zg, 80.f));     // tanh(zg)=(eg-1)/(eg+1)
            // c' = sig(zf)*c + sig(zi)*tanh(zg)   (one rcp for the fused product)
            float cc = cst[r] * frcp(1.f + ef)
                     + (eg - 1.f) * frcp((1.f + ei) * (eg + 1.f));
            cst[r] = cc;
            float ec = __expf(fminf(2.f * cc, 80.f));
            hnew[r] = (ec - 1.f) * frcp((1.f + eo) * (ec + 1.f));  // sig(zo)*tanh(c')
        }
        uint2 st;
        st.x = (u32)f2bf(hnew[0]) | ((u32)f2bf(hnew[1]) << 16);
        st.y = (u32)f2bf(hnew[2]) | ((u32)f2bf(hnew[3]) << 16);
        *(uint2*)&hbuf[cur ^ 1][cn][chb] = st;
        *(uint2*)(ho + ((size_t)s * 64 + b) * 128 + chb) = st;
        #pragma unroll
        for (int mi = 0; mi < 4; ++mi) xc[mi] = xn[mi];
        __syncthreads();
    }
}

// ---------------------------------------------------------------------------
// K3: feats[s,b,t] = [hf|hb] . w_out[t] + b_out[t].   block handles 32 pos.
// ---------------------------------------------------------------------------
__global__ __launch_bounds__(256) void k_feats(
    const u16* __restrict__ hf, const u16* __restrict__ hb,
    const float* __restrict__ wout, const float* __restrict__ bout,
    float* __restrict__ feats)
{
    __shared__ u16 sf[32][136], sb[32][136];
    __shared__ float wo[7][260];
    __shared__ float bo[8];
    int tid = threadIdx.x;
    int pos0 = blockIdx.x * 32;
    {
        int r = tid >> 3, cc = (tid & 7) * 16;
        const uint4* pf = (const uint4*)(hf + (size_t)(pos0 + r) * 128 + cc);
        const uint4* pb = (const uint4*)(hb + (size_t)(pos0 + r) * 128 + cc);
        *(uint4*)&sf[r][cc]     = pf[0];
        *(uint4*)&sf[r][cc + 8] = pf[1];
        *(uint4*)&sb[r][cc]     = pb[0];
        *(uint4*)&sb[r][cc + 8] = pb[1];
    }
    for (int i = tid; i < 1792; i += 256) wo[i >> 8][i & 255] = wout[i];
    if (tid < 7) bo[tid] = bout[tid];
    __syncthreads();
    int pp = tid >> 3, tt = tid & 7;
    if (tt < 7) {
        float acc = bo[tt];
        #pragma unroll 4
        for (int ch = 0; ch < 128; ++ch)
            acc += bf2f(sf[pp][ch]) * wo[tt][ch]
                 + bf2f(sb[pp][ch]) * wo[tt][128 + ch];
        feats[(size_t)(pos0 + pp) * 7 + tt] = acc;
    }
}

// ---------------------------------------------------------------------------
// K4a: CRF chunk fold.  block=(b, chunk of 64 steps): sequential log-space
// matrix product M <- M (x) (T + feat[s]) over the chunk.  512 blocks.
// ---------------------------------------------------------------------------
__global__ __launch_bounds__(64) void k_crf_chunk(
    const float* __restrict__ feats, const float* __restrict__ trans,
    float* __restrict__ chunkM)
{
    int b = blockIdx.x >> 3, c = blockIdx.x & 7;
    int lane = threadIdx.x;
    int i = lane >> 3, j = lane & 7;
    __shared__ float M[8][8];
    __shared__ float fl[64][8];
    int s0 = c * 64;
    for (int idx = lane; idx < 448; idx += 64) {
        int ss = idx / 7, jj = idx - ss * 7;
        fl[ss][jj] = feats[(size_t)((s0 + ss) * 64 + b) * 7 + jj];
    }
    float tc[7];
    #pragma unroll
    for (int k = 0; k < 7; ++k) tc[k] = (j < 7) ? trans[k * 7 + j] : 0.f;
    __syncthreads();
    M[i][j] = (i < 7 && j < 7) ? (trans[i * 7 + j] + fl[0][j]) : -1e30f;
    __syncthreads();
    for (int ss = 1; ss < 64; ++ss) {
        float4 m0 = *(const float4*)&M[i][0];
        float4 m1 = *(const float4*)&M[i][4];
        float v0 = m0.x + tc[0], v1 = m0.y + tc[1], v2 = m0.z + tc[2];
        float v3 = m0.w + tc[3], v4 = m1.x + tc[4], v5 = m1.y + tc[5];
        float v6 = m1.z + tc[6];
        float mx = fmaxf(fmaxf(fmaxf(v0, v1), fmaxf(v2, v3)),
                         fmaxf(fmaxf(v4, v5), v6));
        float sm = __expf(v0 - mx) + __expf(v1 - mx) + __expf(v2 - mx)
                 + __expf(v3 - mx) + __expf(v4 - mx) + __expf(v5 - mx)
                 + __expf(v6 - mx);
        float r = mx + __logf(sm) + fl[ss][j];
        __syncthreads();
        if (i < 7 && j < 7) M[i][j] = r;
        __syncthreads();
    }
    if (i < 7 && j < 7)
        chunkM[(size_t)(b * 8 + c) * 49 + i * 7 + j] = M[i][j];
}

// ---------------------------------------------------------------------------
// K4b: fold 8 chunk matrices with alpha0, add STOP row -> fwd score; compute
// gold score; atomicAdd (fwd-gold)/64 into d_out.  64 blocks (one per batch).
// ---------------------------------------------------------------------------
__global__ __launch_bounds__(64) void k_crf_final(
    const float* __restrict__ chunkM, const float* __restrict__ trans,
    const int* __restrict__ tags, const float* __restrict__ feats,
    float* __restrict__ out)
{
    int b = blockIdx.x;
    int lane = threadIdx.x;
    __shared__ float P[8][49];
    __shared__ float Tl[49];
    __shared__ float av[2][8];
    __shared__ int   tg[512];
    for (int idx = lane; idx < 392; idx += 64)
        P[idx / 49][idx % 49] = chunkM[(size_t)b * 392 + idx];
    if (lane < 49) Tl[lane] = trans[lane];
    for (int idx = lane; idx < 512; idx += 64) tg[idx] = tags[(size_t)b * 512 + idx];
    if (lane < 8) av[0][lane] = (lane == 5) ? 0.f : -1e4f;
    __syncthreads();
    int cur = 0;
    for (int cch = 0; cch < 8; ++cch) {
        if (lane < 7) {
            float vv[7], mx = -1e30f;
            #pragma unroll
            for (int ii = 0; ii < 7; ++ii) {
                vv[ii] = av[cur][ii] + P[cch][ii * 7 + lane];
                mx = fmaxf(mx, vv[ii]);
            }
            float sm = 0.f;
            #pragma unroll
            for (int ii = 0; ii < 7; ++ii) sm += __expf(vv[ii] - mx);
            av[cur ^ 1][lane] = mx + __logf(sm);
        }
        __syncthreads();
        cur ^= 1;
    }
    float mx = -1e30f, uu[7];
    #pragma unroll
    for (int jj = 0; jj < 7; ++jj) {
        uu[jj] = av[cur][jj] + Tl[6 * 7 + jj];
        mx = fmaxf(mx, uu[jj]);
    }
    float sm = 0.f;
    #pragma unroll
    for (int jj = 0; jj < 7; ++jj) sm += __expf(uu[jj] - mx);
    float fwd = mx + __logf(sm);
    // gold
    float acc = 0.f;
    for (int ss = lane; ss < 512; ss += 64) {
        int tn = tg[ss];
        int tp = (ss == 0) ? 5 : tg[ss - 1];
        acc += Tl[tn * 7 + tp] + feats[(size_t)(ss * 64 + b) * 7 + tn];
    }
    #pragma unroll
    for (int mk = 32; mk >= 1; mk >>= 1) acc += __shfl_xor(acc, mk, 64);
    if (lane == 0) {
        float gold = acc + Tl[6 * 7 + tg[511]];
        atomicAdd(out, (fwd - gold) * (1.0f / 64.0f));
    }
}

// ---------------------------------------------------------------------------
extern "C" void kernel_launch(void* const* d_in, const int* in_sizes, int n_in,
                              void* d_out, int out_size, void* d_ws, size_t ws_size,
                              hipStream_t stream) {
    const int*   sent = (const int*)d_in[0];
    const int*   tags = (const int*)d_in[1];
    const float* h0   = (const float*)d_in[2];
    const float* c0   = (const float*)d_in[3];
    const float* emb  = (const float*)d_in[4];
    const float* wihf = (const float*)d_in[5];
    const float* whhf = (const float*)d_in[6];
    const float* bihf = (const float*)d_in[7];
    const float* bhhf = (const float*)d_in[8];
    const float* wihb = (const float*)d_in[9];
    const float* whhb = (const float*)d_in[10];
    const float* bihb = (const float*)d_in[11];
    const float* bhhb = (const float*)d_in[12];
    const float* wout = (const float*)d_in[13];
    const float* bout = (const float*)d_in[14];
    const float* trn  = (const float*)d_in[15];

    char* ws = (char*)d_ws;
    u16*   Xf     = (u16*)(ws);                       // 33,554,432 B
    u16*   Xb     = (u16*)(ws + 33554432);            // 33,554,432 B
    u16*   hfp    = (u16*)(ws + 67108864);            //  8,388,608 B
    u16*   hbp    = (u16*)(ws + 75497472);            //  8,388,608 B
    float* feats  = (float*)(ws + 83886080);          //    917,504 B
    float* chunkM = (float*)(ws + 84803584);          //    100,352 B

    hipMemsetAsync(d_out, 0, 4, stream);
    k_inproj<<<2048, 256, 0, stream>>>(sent, emb, wihf, bihf, bhhf, Xf);
    k_inproj<<<2048, 256, 0, stream>>>(sent, emb, wihb, bihb, bhhb, Xb);
    k_lstm<<<8, 512, 0, stream>>>(h0, c0, whhf, whhb, Xf, Xb, hfp, hbp);
    k_feats<<<1024, 256, 0, stream>>>(hfp, hbp, wout, bout, feats);
    k_crf_chunk<<<512, 64, 0, stream>>>(feats, trn, chunkM);
    k_crf_final<<<64, 64, 0, stream>>>(chunkM, trn, tags, feats, (float*)d_out);
}

// Round 2
// 734.003 us; speedup vs baseline: 1.5355x; 1.5355x over previous
//
#include <hip/hip_runtime.h>

typedef unsigned int u32;
typedef unsigned short u16;
typedef __attribute__((ext_vector_type(8))) short short8;   // 8 bf16 (4 VGPRs)
typedef __attribute__((ext_vector_type(4))) float f32x4;
typedef __attribute__((ext_vector_type(2))) float f32x2;

#define DEV __device__ __forceinline__

DEV u16 f2bf(float f) {
    u32 u = __float_as_uint(f);
    return (u16)((u + 0x7FFFu + ((u >> 16) & 1u)) >> 16);
}
DEV float bf2f(u16 h) { return __uint_as_float(((u32)h) << 16); }
DEV float frcp(float x) { return __builtin_amdgcn_rcpf(x); }

DEV u32 pack_bf16(float a, float b) {
#if __has_builtin(__builtin_amdgcn_cvt_pk_bf16_f32)
    auto v = __builtin_amdgcn_cvt_pk_bf16_f32(a, b);   // lo=a, hi=b
    u32 r; __builtin_memcpy(&r, &v, 4); return r;
#else
    return (u32)f2bf(a) | ((u32)f2bf(b) << 16);
#endif
}

DEV f32x2 exp2x(f32x2 a) { f32x2 r; r.x = __expf(a.x); r.y = __expf(a.y); return r; }
DEV f32x2 rcp2x(f32x2 a) { f32x2 r; r.x = frcp(a.x); r.y = frcp(a.y); return r; }
DEV f32x2 min2s(f32x2 a, float b) { f32x2 r; r.x = fminf(a.x, b); r.y = fminf(a.y, b); return r; }
DEV f32x2 mk2(float a, float b) { f32x2 r; r.x = a; r.y = b; return r; }
DEV float bflo(u32 u) { return __uint_as_float(u << 16); }
DEV float bfhi(u32 u) { return __uint_as_float(u & 0xFFFF0000u); }

// ---------------------------------------------------------------------------
// K1: fused embedding gather + input projection, MFMA version, both dirs.
// grid = 512: blockIdx = dir*256 + g4*64 + schunk.  Each block: 8 s-steps x
// 16 batch x 512 gates.  Weights in bf16 A-frags (same fragment layout as
// k_lstm); emb tile staged bf16 in LDS; X written in C-frag-swizzled layout.
// ---------------------------------------------------------------------------
__global__ __launch_bounds__(512) void k_inproj2(
    const int* __restrict__ sent, const float* __restrict__ emb,
    const float* __restrict__ wihf, const float* __restrict__ bihf, const float* __restrict__ bhhf,
    const float* __restrict__ wihb, const float* __restrict__ bihb, const float* __restrict__ bhhb,
    u16* __restrict__ Xf, u16* __restrict__ Xb)
{
    int blk = blockIdx.x;
    int d  = blk >> 8;
    int g4 = (blk >> 6) & 3;
    int sc = blk & 63;
    const float* wih = d ? wihb : wihf;
    const float* bih = d ? bihb : bihf;
    const float* bhh = d ? bhhb : bhhf;
    u16* X = d ? Xb : Xf;
    int tid = threadIdx.x;
    int w = tid >> 6, lane = tid & 63;
    int rg = lane >> 4, cn = lane & 15;

    // A-fragments from w_ih (bf16).  A[m=lane&15][k=(lane>>4)*8+j]
    short8 afr[4][4];
    #pragma unroll
    for (int mi = 0; mi < 4; ++mi) {
        int gate = 16 * (w + 8 * mi) + cn;
        #pragma unroll
        for (int kt = 0; kt < 4; ++kt) {
            const float* p = wih + (size_t)gate * 128 + kt * 32 + rg * 8;
            float4 f0 = *(const float4*)p;
            float4 f1 = *(const float4*)(p + 4);
            union { short8 v; u32 u[4]; } sv;
            sv.u[0] = pack_bf16(f0.x, f0.y);
            sv.u[1] = pack_bf16(f0.z, f0.w);
            sv.u[2] = pack_bf16(f1.x, f1.y);
            sv.u[3] = pack_bf16(f1.z, f1.w);
            afr[mi][kt] = sv.v;
        }
    }
    float bs[4][4];
    #pragma unroll
    for (int mi = 0; mi < 4; ++mi)
        #pragma unroll
        for (int r = 0; r < 4; ++r) {
            int g = 16 * (w + 8 * mi) + 4 * rg + r;
            bs[mi][r] = bih[g] + bhh[g];
        }

    __shared__ int toks[128];
    __shared__ u16 tile[8][16][136];
    if (tid < 128)
        toks[tid] = sent[(sc * 8 + (tid >> 4)) * 64 + g4 * 16 + (tid & 15)];
    __syncthreads();
    {
        int rr = tid >> 2, q = tid & 3;      // row 0..127, quarter of 128 floats
        int ss = rr >> 4, nn = rr & 15;
        const float* er = emb + (size_t)toks[rr] * 128 + q * 32;
        u16* dst = &tile[ss][nn][q * 32];
        #pragma unroll
        for (int u = 0; u < 4; ++u) {
            float4 a = *(const float4*)(er + u * 8);
            float4 c = *(const float4*)(er + u * 8 + 4);
            uint4 st;
            st.x = pack_bf16(a.x, a.y); st.y = pack_bf16(a.z, a.w);
            st.z = pack_bf16(c.x, c.y); st.w = pack_bf16(c.z, c.w);
            *(uint4*)(dst + u * 8) = st;
        }
    }
    __syncthreads();

    for (int ss = 0; ss < 8; ++ss) {
        short8 bfr[4];                       // B[k][n=cn]
        #pragma unroll
        for (int kt = 0; kt < 4; ++kt)
            bfr[kt] = *(const short8*)&tile[ss][cn][kt * 32 + rg * 8];
        int s = sc * 8 + ss;
        #pragma unroll
        for (int mi = 0; mi < 4; ++mi) {
            f32x4 acc = {0.f, 0.f, 0.f, 0.f};
            #pragma unroll
            for (int kt = 0; kt < 4; ++kt)
                acc = __builtin_amdgcn_mfma_f32_16x16x32_bf16(afr[mi][kt], bfr[kt], acc, 0, 0, 0);
            size_t base = (((size_t)s * 4 + g4) * 32 + (w + 8 * mi)) * 256
                        + (size_t)rg * 64 + (size_t)cn * 4;
            uint2 st;
            st.x = pack_bf16(acc[0] + bs[mi][0], acc[1] + bs[mi][1]);
            st.y = pack_bf16(acc[2] + bs[mi][2], acc[3] + bs[mi][3]);
            *(uint2*)(X + base) = st;
        }
    }
}

// ---------------------------------------------------------------------------
// K2: bidirectional LSTM recurrence.  8 blocks = 2 dirs x 4 batch-groups(16).
// W_hh in per-wave A-fragments (VGPRs); h round-trips a double-buffered LDS
// tile per step; c in registers.  Global h-store AFTER the barrier so its
// vmcnt retires during the next step.  X prefetch via pointer increment.
// ---------------------------------------------------------------------------
__global__ __launch_bounds__(512) void k_lstm(
    const float* __restrict__ h0, const float* __restrict__ c0,
    const float* __restrict__ whhf, const float* __restrict__ whhb,
    const u16* __restrict__ Xf, const u16* __restrict__ Xb,
    u16* __restrict__ hfo, u16* __restrict__ hbo)
{
    int d  = blockIdx.x >> 2, g4 = blockIdx.x & 3;
    const float* whh = d ? whhb : whhf;
    const u16*   X   = d ? Xb   : Xf;
    u16*         ho  = d ? hbo  : hfo;
    int w = threadIdx.x >> 6, lane = threadIdx.x & 63;
    int rg = lane >> 4, cn = lane & 15;

    short8 afr[4][4];
    #pragma unroll
    for (int mi = 0; mi < 4; ++mi) {
        int gate = 16 * (w + 8 * mi) + cn;
        #pragma unroll
        for (int kt = 0; kt < 4; ++kt) {
            const float* p = whh + (size_t)gate * 128 + kt * 32 + rg * 8;
            float4 f0 = *(const float4*)p;
            float4 f1 = *(const float4*)(p + 4);
            union { short8 v; u32 u[4]; } sv;
            sv.u[0] = pack_bf16(f0.x, f0.y);
            sv.u[1] = pack_bf16(f0.z, f0.w);
            sv.u[2] = pack_bf16(f1.x, f1.y);
            sv.u[3] = pack_bf16(f1.z, f1.w);
            afr[mi][kt] = sv.v;
        }
    }
    int b = g4 * 16 + cn;
    int chb = 16 * w + rg * 4;
    f32x2 cp[2];
    {
        float4 cv = *(const float4*)(c0 + ((size_t)d * 64 + b) * 128 + chb);
        cp[0] = mk2(cv.x, cv.y); cp[1] = mk2(cv.z, cv.w);
    }
    __shared__ u16 hbuf[2][16][136];
    {
        float4 hv = *(const float4*)(h0 + ((size_t)d * 64 + b) * 128 + chb);
        uint2 st0;
        st0.x = pack_bf16(hv.x, hv.y);
        st0.y = pack_bf16(hv.z, hv.w);
        *(uint2*)&hbuf[0][cn][chb] = st0;
    }
    __syncthreads();

    int s0 = d ? 511 : 0;
    const int sdelta = d ? -32768 : 32768;      // X u16 elems per s-step
    const ptrdiff_t hdelta = d ? -8192 : 8192;  // 64*128 u16 per s-step
    size_t lof = (size_t)rg * 64 + (size_t)cn * 4;
    const u16* xp[4];
    uint2 xc[4];
    #pragma unroll
    for (int mi = 0; mi < 4; ++mi) {
        xp[mi] = X + (((size_t)s0 * 4 + g4) * 32 + (w + 8 * mi)) * 256 + lof;
        xc[mi] = *(const uint2*)xp[mi];
    }
    u16* hop = ho + ((size_t)s0 * 64 + b) * 128 + chb;
    const u16* hr0 = &hbuf[0][cn][0];
    const u16* hr1 = &hbuf[1][cn][0];
    u16* hw0 = &hbuf[0][cn][chb];
    u16* hw1 = &hbuf[1][cn][chb];

    for (int t = 0; t < 512; ++t) {
        uint2 xn[4];                            // prefetch next step's X
        #pragma unroll
        for (int mi = 0; mi < 4; ++mi) {
            xp[mi] += sdelta;
            xn[mi] = *(const uint2*)xp[mi];
        }
        int cur = t & 1;
        const u16* rrow = cur ? hr1 : hr0;
        short8 bfr[4];                          // B[k][n]
        #pragma unroll
        for (int kt = 0; kt < 4; ++kt)
            bfr[kt] = *(const short8*)(rrow + kt * 32 + rg * 8);

        f32x4 z[4];
        #pragma unroll
        for (int mi = 0; mi < 4; ++mi) {
            f32x4 acc = {0.f, 0.f, 0.f, 0.f};
            #pragma unroll
            for (int kt = 0; kt < 4; ++kt)
                acc = __builtin_amdgcn_mfma_f32_16x16x32_bf16(afr[mi][kt], bfr[kt], acc, 0, 0, 0);
            z[mi] = acc;
        }

        f32x2 hv2[2];
        #pragma unroll
        for (int p = 0; p < 2; ++p) {
            u32 u0 = p ? xc[0].y : xc[0].x;
            u32 u1 = p ? xc[1].y : xc[1].x;
            u32 u2 = p ? xc[2].y : xc[2].x;
            u32 u3 = p ? xc[3].y : xc[3].x;
            int r0 = 2 * p;
            f32x2 zi = mk2(z[0][r0], z[0][r0 + 1]) + mk2(bflo(u0), bfhi(u0));
            f32x2 zf = mk2(z[1][r0], z[1][r0 + 1]) + mk2(bflo(u1), bfhi(u1));
            f32x2 zg = mk2(z[2][r0], z[2][r0 + 1]) + mk2(bflo(u2), bfhi(u2));
            f32x2 zo = mk2(z[3][r0], z[3][r0 + 1]) + mk2(bflo(u3), bfhi(u3));
            f32x2 ei = exp2x(-zi);
            f32x2 ef = exp2x(-zf);
            f32x2 eo = exp2x(-zo);
            f32x2 eg = exp2x(min2s(zg + zg, 80.f));
            f32x2 A = ei + 1.f, F = ef + 1.f, G = eg + 1.f, O = eo + 1.f;
            f32x2 AG = A * G;
            // c' = c*sig(zf) + sig(zi)*tanh(zg) = (c*A*G + (eg-1)*F)/(F*A*G)
            f32x2 num = cp[p] * AG + (eg - 1.f) * F;
            f32x2 cc = num * rcp2x(F * AG);
            cp[p] = cc;
            f32x2 ec = exp2x(min2s(cc + cc, 80.f));
            hv2[p] = (ec - 1.f) * rcp2x(O * (ec + 1.f));   // sig(zo)*tanh(c')
        }
        uint2 st;
        st.x = pack_bf16(hv2[0].x, hv2[0].y);
        st.y = pack_bf16(hv2[1].x, hv2[1].y);
        u16* wrow = cur ? hw0 : hw1;            // write the OTHER buffer
        *(uint2*)wrow = st;
        __syncthreads();
        *(uint2*)hop = st;                      // post-barrier: retires async
        hop += hdelta;
        #pragma unroll
        for (int mi = 0; mi < 4; ++mi) xc[mi] = xn[mi];
    }
}

// ---------------------------------------------------------------------------
// K3: feats[s,b,t] = [hf|hb] . w_out[t] + b_out[t].   block handles 32 pos.
// ---------------------------------------------------------------------------
__global__ __launch_bounds__(256) void k_feats(
    const u16* __restrict__ hf, const u16* __restrict__ hb,
    const float* __restrict__ wout, const float* __restrict__ bout,
    float* __restrict__ feats)
{
    __shared__ u16 sf[32][136], sb[32][136];
    __shared__ float wo[7][260];
    __shared__ float bo[8];
    int tid = threadIdx.x;
    int pos0 = blockIdx.x * 32;
    {
        int r = tid >> 3, cc = (tid & 7) * 16;
        const uint4* pf = (const uint4*)(hf + (size_t)(pos0 + r) * 128 + cc);
        const uint4* pb = (const uint4*)(hb + (size_t)(pos0 + r) * 128 + cc);
        *(uint4*)&sf[r][cc]     = pf[0];
        *(uint4*)&sf[r][cc + 8] = pf[1];
        *(uint4*)&sb[r][cc]     = pb[0];
        *(uint4*)&sb[r][cc + 8] = pb[1];
    }
    for (int i = tid; i < 1792; i += 256) wo[i >> 8][i & 255] = wout[i];
    if (tid < 7) bo[tid] = bout[tid];
    __syncthreads();
    int pp = tid >> 3, tt = tid & 7;
    if (tt < 7) {
        float acc = bo[tt];
        #pragma unroll 4
        for (int ch = 0; ch < 128; ++ch)
            acc += bf2f(sf[pp][ch]) * wo[tt][ch]
                 + bf2f(sb[pp][ch]) * wo[tt][128 + ch];
        feats[(size_t)(pos0 + pp) * 7 + tt] = acc;
    }
}

// ---------------------------------------------------------------------------
// K4a: CRF chunk fold.  block=(b, chunk of 64 steps): sequential log-space
// matrix product M <- M (x) (T + feat[s]) over the chunk.  512 blocks.
// ---------------------------------------------------------------------------
__global__ __launch_bounds__(64) void k_crf_chunk(
    const float* __restrict__ feats, const float* __restrict__ trans,
    float* __restrict__ chunkM)
{
    int b = blockIdx.x >> 3, c = blockIdx.x & 7;
    int lane = threadIdx.x;
    int i = lane >> 3, j = lane & 7;
    __shared__ float M[8][8];
    __shared__ float fl[64][8];
    int s0 = c * 64;
    for (int idx = lane; idx < 448; idx += 64) {
        int ss = idx / 7, jj = idx - ss * 7;
        fl[ss][jj] = feats[(size_t)((s0 + ss) * 64 + b) * 7 + jj];
    }
    float tc[7];
    #pragma unroll
    for (int k = 0; k < 7; ++k) tc[k] = (j < 7) ? trans[k * 7 + j] : 0.f;
    __syncthreads();
    M[i][j] = (i < 7 && j < 7) ? (trans[i * 7 + j] + fl[0][j]) : -1e30f;
    __syncthreads();
    for (int ss = 1; ss < 64; ++ss) {
        float4 m0 = *(const float4*)&M[i][0];
        float4 m1 = *(const float4*)&M[i][4];
        float v0 = m0.x + tc[0], v1 = m0.y + tc[1], v2 = m0.z + tc[2];
        float v3 = m0.w + tc[3], v4 = m1.x + tc[4], v5 = m1.y + tc[5];
        float v6 = m1.z + tc[6];
        float mx = fmaxf(fmaxf(fmaxf(v0, v1), fmaxf(v2, v3)),
                         fmaxf(fmaxf(v4, v5), v6));
        float sm = __expf(v0 - mx) + __expf(v1 - mx) + __expf(v2 - mx)
                 + __expf(v3 - mx) + __expf(v4 - mx) + __expf(v5 - mx)
                 + __expf(v6 - mx);
        float r = mx + __logf(sm) + fl[ss][j];
        __syncthreads();
        if (i < 7 && j < 7) M[i][j] = r;
        __syncthreads();
    }
    if (i < 7 && j < 7)
        chunkM[(size_t)(b * 8 + c) * 49 + i * 7 + j] = M[i][j];
}

// ---------------------------------------------------------------------------
// K4b: fold 8 chunk matrices with alpha0, add STOP row -> fwd score; compute
// gold score; atomicAdd (fwd-gold)/64 into d_out.  64 blocks (one per batch).
// ---------------------------------------------------------------------------
__global__ __launch_bounds__(64) void k_crf_final(
    const float* __restrict__ chunkM, const float* __restrict__ trans,
    const int* __restrict__ tags, const float* __restrict__ feats,
    float* __restrict__ out)
{
    int b = blockIdx.x;
    int lane = threadIdx.x;
    __shared__ float P[8][49];
    __shared__ float Tl[49];
    __shared__ float av[2][8];
    __shared__ int   tg[512];
    for (int idx = lane; idx < 392; idx += 64)
        P[idx / 49][idx % 49] = chunkM[(size_t)b * 392 + idx];
    if (lane < 49) Tl[lane] = trans[lane];
    for (int idx = lane; idx < 512; idx += 64) tg[idx] = tags[(size_t)b * 512 + idx];
    if (lane < 8) av[0][lane] = (lane == 5) ? 0.f : -1e4f;
    __syncthreads();
    int cur = 0;
    for (int cch = 0; cch < 8; ++cch) {
        if (lane < 7) {
            float vv[7], mx = -1e30f;
            #pragma unroll
            for (int ii = 0; ii < 7; ++ii) {
                vv[ii] = av[cur][ii] + P[cch][ii * 7 + lane];
                mx = fmaxf(mx, vv[ii]);
            }
            float sm = 0.f;
            #pragma unroll
            for (int ii = 0; ii < 7; ++ii) sm += __expf(vv[ii] - mx);
            av[cur ^ 1][lane] = mx + __logf(sm);
        }
        __syncthreads();
        cur ^= 1;
    }
    float mx = -1e30f, uu[7];
    #pragma unroll
    for (int jj = 0; jj < 7; ++jj) {
        uu[jj] = av[cur][jj] + Tl[6 * 7 + jj];
        mx = fmaxf(mx, uu[jj]);
    }
    float sm = 0.f;
    #pragma unroll
    for (int jj = 0; jj < 7; ++jj) sm += __expf(uu[jj] - mx);
    float fwd = mx + __logf(sm);
    float acc = 0.f;
    for (int ss = lane; ss < 512; ss += 64) {
        int tn = tg[ss];
        int tp = (ss == 0) ? 5 : tg[ss - 1];
        acc += Tl[tn * 7 + tp] + feats[(size_t)(ss * 64 + b) * 7 + tn];
    }
    #pragma unroll
    for (int mk = 32; mk >= 1; mk >>= 1) acc += __shfl_xor(acc, mk, 64);
    if (lane == 0) {
        float gold = acc + Tl[6 * 7 + tg[511]];
        atomicAdd(out, (fwd - gold) * (1.0f / 64.0f));
    }
}

// ---------------------------------------------------------------------------
extern "C" void kernel_launch(void* const* d_in, const int* in_sizes, int n_in,
                              void* d_out, int out_size, void* d_ws, size_t ws_size,
                              hipStream_t stream) {
    const int*   sent = (const int*)d_in[0];
    const int*   tags = (const int*)d_in[1];
    const float* h0   = (const float*)d_in[2];
    const float* c0   = (const float*)d_in[3];
    const float* emb  = (const float*)d_in[4];
    const float* wihf = (const float*)d_in[5];
    const float* whhf = (const float*)d_in[6];
    const float* bihf = (const float*)d_in[7];
    const float* bhhf = (const float*)d_in[8];
    const float* wihb = (const float*)d_in[9];
    const float* whhb = (const float*)d_in[10];
    const float* bihb = (const float*)d_in[11];
    const float* bhhb = (const float*)d_in[12];
    const float* wout = (const float*)d_in[13];
    const float* bout = (const float*)d_in[14];
    const float* trn  = (const float*)d_in[15];

    char* ws = (char*)d_ws;
    u16*   Xf     = (u16*)(ws);                       // 33,554,432 B
    u16*   Xb     = (u16*)(ws + 33554432);            // 33,554,432 B
    u16*   hfp    = (u16*)(ws + 67108864);            //  8,388,608 B
    u16*   hbp    = (u16*)(ws + 75497472);            //  8,388,608 B
    float* feats  = (float*)(ws + 83886080);          //    917,504 B
    float* chunkM = (float*)(ws + 84803584);          //    100,352 B

    hipMemsetAsync(d_out, 0, 4, stream);
    k_inproj2<<<512, 512, 0, stream>>>(sent, emb, wihf, bihf, bhhf,
                                       wihb, bihb, bhhb, Xf, Xb);
    k_lstm<<<8, 512, 0, stream>>>(h0, c0, whhf, whhb, Xf, Xb, hfp, hbp);
    k_feats<<<1024, 256, 0, stream>>>(hfp, hbp, wout, bout, feats);
    k_crf_chunk<<<512, 64, 0, stream>>>(feats, trn, chunkM);
    k_crf_final<<<64, 64, 0, stream>>>(chunkM, trn, tags, feats, (float*)d_out);
}